// Round 25
// baseline (87.421 us; speedup 1.0000x reference)
//
#include <hip/hip_runtime.h>
#include <math.h>

typedef unsigned short u16;
typedef unsigned int u32;
typedef __attribute__((ext_vector_type(8))) short bf16x8;
typedef __attribute__((ext_vector_type(4))) short short4v;
typedef __attribute__((ext_vector_type(4))) float f32x4;
typedef __attribute__((ext_vector_type(16))) float f32x16;

#define HW32 1024
#define HW64 4096
#define KCAM 21
#define PB 64
#define PSPLIT 4
#define FT_STR 168   // u16 LDS row stride (160 + 8 pad)
#define XI_STR 136   // u16 LDS row stride for xin (128 + 8 pad)
#define C32_STR 104  // u16 LDS row stride for c32 (96 + 8 pad)

// async global->LDS, 16B per lane, linear dest (wave-uniform base + lane*16)
#define GLOAD_LDS16(gsrc, ldst)                                                \
  __builtin_amdgcn_global_load_lds(                                            \
      (const __attribute__((address_space(1))) void*)(gsrc),                   \
      (__attribute__((address_space(3))) void*)(ldst), 16, 0, 0)

static __device__ __forceinline__ u16 f2bf(float x) {
  u32 u = __float_as_uint(x);
  u32 r = (u + 0x7FFFu + ((u >> 16) & 1u)) >> 16;
  return (u16)r;
}
static __device__ __forceinline__ float bf2f(u16 h) {
  return __uint_as_float(((u32)h) << 16);
}

// ---------------------------------------------------------------------------
// Kernel B: build normalized f via MFMA with convs folded in, 1024 threads
// (R24 proven). LDS: wh 42 + wl 42 + featA 42 (aliases xin) + c32 26.6 KB.
// ---------------------------------------------------------------------------
__global__ __launch_bounds__(1024) void k_build_f(
    const float* __restrict__ inp, const float* __restrict__ aspp,
    const float* __restrict__ f3g, const float* __restrict__ w_aspp,
    const float* __restrict__ w_f3, const float* __restrict__ w_f9,
    const float* __restrict__ cam,
    u16* __restrict__ fhi_g, u16* __restrict__ camA)
{
  const int y2 = blockIdx.x, n = blockIdx.y;
  const int tid = threadIdx.x;

  __shared__ __align__(16) u16 wh[128 * FT_STR];
  __shared__ __align__(16) u16 wl[128 * FT_STR];
  __shared__ __align__(16) u16 featA[128 * FT_STR];   // first used as xin
  __shared__ __align__(16) u16 c32[128 * C32_STR];    // [which*64+ch][px96]

  u16* xin = featA;   // xin[j(px96)][ch128], stride XI_STR; dead before feat

  // ---- P0: inline w_f9 split (k range padded to 160 with zeros)
  for (int e = tid; e < 128 * 160; e += 1024) {
    const int o = e / 160, c = e - o * 160;
    const float v = (c < 132) ? w_f9[o * 132 + c] : 0.f;
    const u16 h = f2bf(v);
    wh[o * FT_STR + c] = h;
    wl[o * FT_STR + c] = f2bf(v - bf2f(h));
  }
  // ---- camA side job
  {
    u16* dst = camA + ((size_t)n * 32 + y2) * HW64;
    if (y2 < KCAM) {
      const float* src = cam + ((size_t)n * KCAM + y2) * HW64;
      for (int i = tid; i < HW64; i += 1024) dst[i] = f2bf(src[i]);
    } else {
      const u16 v = (y2 == KCAM) ? f2bf(1.f) : (u16)0;
      for (int i = tid; i < HW64; i += 1024) dst[i] = v;
    }
  }

  // ---- bilinear params
  const float s512 = 511.f / 63.f, s32 = 31.f / 63.f;
  const int yA0i = y2 * 2, yA1i = y2 * 2 + 1;
  const float sA0 = yA0i * s512, sA1 = yA1i * s512;
  const int y0A0 = (int)sA0, y0A1 = (int)sA1;
  const float wyA0 = sA0 - y0A0, wyA1 = sA1 - y0A1;
  const int y1A0 = min(y0A0 + 1, 511), y1A1 = min(y0A1 + 1, 511);
  const float sB0 = yA0i * s32, sB1 = yA1i * s32;
  const int y0B0 = (int)sB0, y0B1 = (int)sB1;
  const float wyB0 = sB0 - y0B0, wyB1 = sB1 - y0B1;
  const int y1B0 = min(y0B0 + 1, 31), y1B1 = min(y0B1 + 1, 31);

  const int r0 = y0B0;
  const int sl0B0 = 0;
  const int sl1B0 = y1B0 - r0;
  const int sl0B1 = y0B1 - r0;
  const int sl1B1 = y1B1 - r0;

  const int lane = tid & 63, wave = tid >> 6;   // 16 waves
  const int l15 = lane & 15, l4 = lane >> 4;

  const int cm = wave & 3, chalf = (wave >> 2) & 1;

  // ---- P1/P2 (aspp) then P3/P4 (f3)
#pragma unroll
  for (int which = 0; which < 2; ++which) {
    const float* src = (which == 0 ? aspp : f3g) + (size_t)n * 128 * HW32;
    const float* wsrc = (which == 0 ? w_aspp : w_f3);

    for (int e = tid; e < 128 * 96; e += 1024) {
      const int ch = e / 96, j = e - ch * 96;
      const int rr = min(r0 + (j >> 5), 31);
      xin[j * XI_STR + ch] = f2bf(src[(size_t)ch * HW32 + rr * 32 + (j & 31)]);
    }
    __syncthreads();

    if (wave < 8) {
      f32x4 cacc[3];
#pragma unroll
      for (int pt = 0; pt < 3; ++pt) cacc[pt] = {0.f, 0.f, 0.f, 0.f};
#pragma unroll
      for (int s = 0; s < 4; ++s) {
        union { u16 h[8]; bf16x8 v; } Ahi, Alo;
        const float* wrow = wsrc + (cm * 16 + l15) * 128 + s * 32 + l4 * 8;
#pragma unroll
        for (int e = 0; e < 8; ++e) {
          const float v = wrow[e];
          const u16 h = f2bf(v);
          Ahi.h[e] = h;
          Alo.h[e] = f2bf(v - bf2f(h));
        }
#pragma unroll
        for (int pt = 0; pt < 3; ++pt) {
          const int px = (chalf * 3 + pt) * 16 + l15;
          const bf16x8 B = *(const bf16x8*)&xin[px * XI_STR + s * 32 + l4 * 8];
          cacc[pt] = __builtin_amdgcn_mfma_f32_16x16x32_bf16(Ahi.v, B, cacc[pt], 0, 0, 0);
          cacc[pt] = __builtin_amdgcn_mfma_f32_16x16x32_bf16(Alo.v, B, cacc[pt], 0, 0, 0);
        }
      }
#pragma unroll
      for (int pt = 0; pt < 3; ++pt) {
        const int px = (chalf * 3 + pt) * 16 + l15;
#pragma unroll
        for (int i = 0; i < 4; ++i)
          c32[(which * 64 + cm * 16 + l4 * 4 + i) * C32_STR + px] =
              f2bf(cacc[pt][i]);
      }
    }
    __syncthreads();
  }

  // ---- P5: feat sampling (c<4 global inp; c>=4 from c32 LDS)
  for (int idx = tid; idx < 132 * 128; idx += 1024) {
    const int c = idx >> 7;
    const int pos = idx & 127;
    const int ly = pos >> 6, x = pos & 63;
    float v;
    if (c < 4) {
      const int y0A = ly ? y0A1 : y0A0, y1A = ly ? y1A1 : y1A0;
      const float wyA = ly ? wyA1 : wyA0;
      const float sx = x * s512;
      const int x0 = (int)sx;
      const float wx = sx - (float)x0;
      const int x1 = min(x0 + 1, 511);
      const float* im = inp + (size_t)(n * 4 + c) * 512 * 512;
      const float v00 = im[y0A * 512 + x0], v01 = im[y0A * 512 + x1];
      const float v10 = im[y1A * 512 + x0], v11 = im[y1A * 512 + x1];
      v = (v00 * (1.f - wx) + v01 * wx) * (1.f - wyA) +
          (v10 * (1.f - wx) + v11 * wx) * wyA;
    } else {
      const int wh_ = (c < 68) ? 0 : 1;
      const int cc = (c < 68) ? (c - 4) : (c - 68);
      const int s0 = ly ? sl0B1 : sl0B0;
      const int s1 = ly ? sl1B1 : sl1B0;
      const float wyB = ly ? wyB1 : wyB0;
      const float sx = x * s32;
      const int x0 = (int)sx;
      const float wx = sx - (float)x0;
      const int x1 = min(x0 + 1, 31);
      const u16* row = &c32[(wh_ * 64 + cc) * C32_STR];
      const float v00 = bf2f(row[s0 * 32 + x0]), v01 = bf2f(row[s0 * 32 + x1]);
      const float v10 = bf2f(row[s1 * 32 + x0]), v11 = bf2f(row[s1 * 32 + x1]);
      v = (v00 * (1.f - wx) + v01 * wx) * (1.f - wyB) +
          (v10 * (1.f - wx) + v11 * wx) * wyB;
    }
    featA[pos * FT_STR + c] = f2bf(v);
  }
  for (int idx = tid; idx < 28 * 128; idx += 1024) {
    const int c = 132 + (idx >> 7), pos = idx & 127;
    featA[pos * FT_STR + c] = 0;
  }
  __syncthreads();

  // ---- P6: main MFMA (waves 0..7, each owns 16 positions), norm, store
  if (wave < 8) {
    float acc[8][4];
#pragma unroll
    for (int m = 0; m < 8; ++m)
#pragma unroll
      for (int i = 0; i < 4; ++i) acc[m][i] = 0.f;

#pragma unroll
    for (int s = 0; s < 5; ++s) {
      const bf16x8 B =
          *(const bf16x8*)&featA[(wave * 16 + l15) * FT_STR + s * 32 + l4 * 8];
#pragma unroll
      for (int m = 0; m < 8; ++m) {
        const int wo = (m * 16 + l15) * FT_STR + s * 32 + l4 * 8;
        const bf16x8 Ahi = *(const bf16x8*)&wh[wo];
        const bf16x8 Alo = *(const bf16x8*)&wl[wo];
        f32x4 a = {acc[m][0], acc[m][1], acc[m][2], acc[m][3]};
        a = __builtin_amdgcn_mfma_f32_16x16x32_bf16(Ahi, B, a, 0, 0, 0);
        a = __builtin_amdgcn_mfma_f32_16x16x32_bf16(Alo, B, a, 0, 0, 0);
        acc[m][0] = a[0]; acc[m][1] = a[1]; acc[m][2] = a[2]; acc[m][3] = a[3];
      }
    }

    float ss = 0.f;
#pragma unroll
    for (int m = 0; m < 8; ++m)
#pragma unroll
      for (int i = 0; i < 4; ++i) ss = fmaf(acc[m][i], acc[m][i], ss);
    ss += __shfl_xor(ss, 16);
    ss += __shfl_xor(ss, 32);
    const float inv = 1.f / (sqrtf(ss) + 1e-5f);
    const int pos = wave * 16 + l15;
    u16* fp = fhi_g + ((size_t)n * HW64 + (size_t)(y2 * 2 + (pos >> 6)) * 64 +
                       (pos & 63)) * 128 + l4 * 4;
#pragma unroll
    for (int m = 0; m < 8; ++m) {
      const float v0 = acc[m][0] * inv, v1 = acc[m][1] * inv;
      const float v2 = acc[m][2] * inv, v3 = acc[m][3] * inv;
      union { u32 d[2]; short4v h; } P;
      asm("v_cvt_pk_bf16_f32 %0, %1, %2" : "=v"(P.d[0]) : "v"(v0), "v"(v1));
      asm("v_cvt_pk_bf16_f32 %0, %1, %2" : "=v"(P.d[1]) : "v"(v2), "v"(v3));
      *(short4v*)(fp + m * 16) = P.h;
    }
  }
}

// ---------------------------------------------------------------------------
// Kernel C: fused affinity+cam, Q-SPLIT FOR TLP: 128 q per block (2 waves),
// grid 1024 = 4ps x 32qt x 8n -> 4 blocks/CU, 4 waves/SIMD at UNCHANGED part
// traffic (the unconfounded occupancy test R14 couldn't give). Per-wave work
// identical to R22 (q64/wave, 32x32x16 MFMA, zero-shuffle stage-2, async
// global_load_lds with pre-swizzled source).
// ---------------------------------------------------------------------------
__global__ __launch_bounds__(128) void k_fused(
    const u16* __restrict__ fhi_g, const u16* __restrict__ camA,
    float* __restrict__ part)
{
  __shared__ __align__(16) u16 fh[2][PB * 128];   // 32 KB

  const int gx = blockIdx.x;
  const int n = gx & 7;
  const int rest = gx >> 3;
  const int qt = rest & 31;            // 32 q-tiles of 128
  const int ps = rest >> 5;
  const int tid = threadIdx.x;
  const int lane = tid & 63;
  const int wq = tid >> 6;             // 0/1
  const int l31 = lane & 31;
  const int lh = lane >> 5;
  const int qb = qt * 128;

  const u16* fbase = fhi_g + (size_t)n * HW64 * 128;

  bf16x8 Bq[2][8];
#pragma unroll
  for (int qh = 0; qh < 2; ++qh) {
    const size_t rowo = (size_t)(qb + wq * 64 + qh * 32 + l31) * 128;
#pragma unroll
    for (int ks = 0; ks < 8; ++ks)
      Bq[qh][ks] = *(const bf16x8*)(fbase + rowo + ks * 16 + lh * 8);
  }

  f32x16 nacc0, nacc1;
#pragma unroll
  for (int i = 0; i < 16; ++i) { nacc0[i] = 0.f; nacc1[i] = 0.f; }

  const int p_base = ps * (HW64 / PSPLIT);
  const int xorr = (l31 & 7) << 4;

  // staging: 2 waves x 8 calls = 16 chunks of 4 rows (64 rows, 16KB)
  const int srow0 = (lane >> 4);          // 0..3 within a chunk
  const int scbl = (lane & 15) * 16;      // byte col in the 256B row

#pragma unroll
  for (int s = 0; s < 8; ++s) {
    const int ck = wq * 8 + s;
    const int rr = ck * 4 + srow0;
    const u16* gsrc = fbase + (size_t)(p_base + rr) * 128 +
                      ((scbl ^ ((rr & 7) << 4)) >> 1);
    GLOAD_LDS16(gsrc, &fh[0][ck * 512]);
  }

  int cur = 0;
  for (int t = 0; t < (HW64 / PSPLIT) / PB; ++t) {   // 16 tiles
    const int p0 = p_base + t * PB;
    __syncthreads();   // vmcnt drained -> buf[cur] ready

    if (t < 15) {
#pragma unroll
      for (int s = 0; s < 8; ++s) {
        const int ck = wq * 8 + s;
        const int rr = ck * 4 + srow0;
        const u16* gsrc = fbase + (size_t)(p0 + PB + rr) * 128 +
                          ((scbl ^ ((rr & 7) << 4)) >> 1);
        GLOAD_LDS16(gsrc, &fh[cur ^ 1][ck * 512]);
      }
    }

    bf16x8 Ac[4];
#pragma unroll
    for (int kst = 0; kst < 4; ++kst) {
      union { short4v h[2]; bf16x8 v; } A;
      const u16* cp = camA + ((size_t)n * 32 + l31) * HW64 + p0 + kst * 16 + lh * 4;
      A.h[0] = *(const short4v*)cp;
      A.h[1] = *(const short4v*)(cp + 8);
      Ac[kst] = A.v;
    }

    f32x16 accS[2][2];
#pragma unroll
    for (int ks = 0; ks < 8; ++ks) {
      const int cb = (ks * 32 + (lh << 4)) ^ xorr;
      bf16x8 Ah[2];
#pragma unroll
      for (int mt = 0; mt < 2; ++mt)
        Ah[mt] = *(const bf16x8*)&fh[cur][(mt * 32 + l31) * 128 + (cb >> 1)];
      if (ks == 0) {
        f32x16 z;
#pragma unroll
        for (int i = 0; i < 16; ++i) z[i] = 0.f;
#pragma unroll
        for (int mt = 0; mt < 2; ++mt) {
          accS[mt][0] = __builtin_amdgcn_mfma_f32_32x32x16_bf16(Ah[mt], Bq[0][0], z, 0, 0, 0);
          accS[mt][1] = __builtin_amdgcn_mfma_f32_32x32x16_bf16(Ah[mt], Bq[1][0], z, 0, 0, 0);
        }
      } else {
#pragma unroll
        for (int mt = 0; mt < 2; ++mt) {
          accS[mt][0] = __builtin_amdgcn_mfma_f32_32x32x16_bf16(Ah[mt], Bq[0][ks], accS[mt][0], 0, 0, 0);
          accS[mt][1] = __builtin_amdgcn_mfma_f32_32x32x16_bf16(Ah[mt], Bq[1][ks], accS[mt][1], 0, 0, 0);
        }
      }
    }

#pragma unroll
    for (int kst = 0; kst < 4; ++kst) {
      const int mt = kst >> 1, h8 = (kst & 1) * 8;
#pragma unroll
      for (int qh = 0; qh < 2; ++qh) {
        union { u32 d[4]; bf16x8 v; } W;
#pragma unroll
        for (int i = 0; i < 4; ++i) {
          const float a0 = fmaxf(accS[mt][qh][h8 + 2 * i], 0.f);
          const float a1 = fmaxf(accS[mt][qh][h8 + 2 * i + 1], 0.f);
          asm("v_cvt_pk_bf16_f32 %0, %1, %2" : "=v"(W.d[i]) : "v"(a0), "v"(a1));
        }
        if (qh == 0)
          nacc0 = __builtin_amdgcn_mfma_f32_32x32x16_bf16(Ac[kst], W.v, nacc0, 0, 0, 0);
        else
          nacc1 = __builtin_amdgcn_mfma_f32_32x32x16_bf16(Ac[kst], W.v, nacc1, 0, 0, 0);
      }
    }

    cur ^= 1;
  }

#pragma unroll
  for (int qh = 0; qh < 2; ++qh) {
    const int qg = qb + wq * 64 + qh * 32 + l31;
#pragma unroll
    for (int r = 0; r < 16; ++r) {
      const int row = (r & 3) + 8 * (r >> 2) + 4 * lh;
      if (row < 22)
        part[(((size_t)n * PSPLIT + ps) * 22 + row) * HW64 + qg] =
            (qh == 0) ? nacc0[r] : nacc1[r];
    }
  }
}

// ---------------------------------------------------------------------------
// Kernel D: combine PSPLIT partials, divide. float4 per thread.
// ---------------------------------------------------------------------------
__global__ __launch_bounds__(256) void k_final(
    const float* __restrict__ part, float* __restrict__ out, int total4)
{
  const int idx = blockIdx.x * 256 + threadIdx.x;
  if (idx >= total4) return;
  const int n = idx / (KCAM * 1024);
  const int r = idx - n * (KCAM * 1024);
  const int k = r >> 10;
  const int q4 = (r & 1023) * 4;
  const float* base = part + (size_t)n * PSPLIT * 22 * HW64;
  float4 num = {0.f, 0.f, 0.f, 0.f}, den = {0.f, 0.f, 0.f, 0.f};
#pragma unroll
  for (int p = 0; p < PSPLIT; ++p) {
    const float4 nv = *reinterpret_cast<const float4*>(
        &base[((size_t)p * 22 + k) * HW64 + q4]);
    const float4 dv = *reinterpret_cast<const float4*>(
        &base[((size_t)p * 22 + 21) * HW64 + q4]);
    num.x += nv.x; num.y += nv.y; num.z += nv.z; num.w += nv.w;
    den.x += dv.x; den.y += dv.y; den.z += dv.z; den.w += dv.w;
  }
  float4 o;
  o.x = num.x / (den.x + 1e-5f);
  o.y = num.y / (den.y + 1e-5f);
  o.z = num.z / (den.z + 1e-5f);
  o.w = num.w / (den.w + 1e-5f);
  *reinterpret_cast<float4*>(&out[((size_t)n * KCAM + k) * HW64 + q4]) = o;
}

// ---------------------------------------------------------------------------
extern "C" void kernel_launch(void* const* d_in, const int* in_sizes, int n_in,
                              void* d_out, int out_size, void* d_ws, size_t ws_size,
                              hipStream_t stream) {
  const float* aspp   = (const float*)d_in[0];
  const float* f3     = (const float*)d_in[1];
  const float* inp    = (const float*)d_in[2];
  const float* cam    = (const float*)d_in[3];
  const float* w_aspp = (const float*)d_in[4];
  const float* w_f3   = (const float*)d_in[5];
  const float* w_f9   = (const float*)d_in[6];
  float* out = (float*)d_out;

  // Workspace (~21.5 MB):
  //   [0, 8MB)    fhi  (u16, 8*4096*128)   k_build_f
  //   [8, 10MB)   camA (u16, 8*32*4096)    k_build_f side job
  //   then part (f32, 8*4*22*4096 = 11.5MB)  k_fused
  u16*   fhi  = (u16*)d_ws;
  u16*   camA = fhi + 4194304;
  float* part = (float*)(camA + 1048576);

  k_build_f<<<dim3(32, 8), 1024, 0, stream>>>(inp, aspp, f3, w_aspp, w_f3,
                                              w_f9, cam, fhi, camA);
  k_fused<<<1024, 128, 0, stream>>>(fhi, camA, part);
  k_final<<<672, 256, 0, stream>>>(part, out, 8 * KCAM * 1024);
}

// Round 26
// 84.343 us; speedup vs baseline: 1.0365x; 1.0365x over previous
//
#include <hip/hip_runtime.h>
#include <math.h>

typedef unsigned short u16;
typedef unsigned int u32;
typedef __attribute__((ext_vector_type(8))) short bf16x8;
typedef __attribute__((ext_vector_type(4))) short short4v;
typedef __attribute__((ext_vector_type(4))) float f32x4;
typedef __attribute__((ext_vector_type(16))) float f32x16;

#define HW32 1024
#define HW64 4096
#define KCAM 21
#define PB 64
#define PSPLIT 4
#define FT_STR 168   // u16 LDS row stride (160 + 8 pad)
#define XI_STR 136   // u16 LDS row stride for xin (128 + 8 pad)
#define C32_STR 104  // u16 LDS row stride for c32 (96 + 8 pad)

// async global->LDS, 16B per lane, linear dest (wave-uniform base + lane*16)
#define GLOAD_LDS16(gsrc, ldst)                                                \
  __builtin_amdgcn_global_load_lds(                                            \
      (const __attribute__((address_space(1))) void*)(gsrc),                   \
      (__attribute__((address_space(3))) void*)(ldst), 16, 0, 0)

static __device__ __forceinline__ u16 f2bf(float x) {
  u32 u = __float_as_uint(x);
  u32 r = (u + 0x7FFFu + ((u >> 16) & 1u)) >> 16;
  return (u16)r;
}
static __device__ __forceinline__ float bf2f(u16 h) {
  return __uint_as_float(((u32)h) << 16);
}

// ---------------------------------------------------------------------------
// Kernel B: build normalized f via MFMA with convs folded in, 1024 threads
// (R24 proven). LDS: wh 42 + wl 42 + featA 42 (aliases xin) + c32 26.6 KB.
// ---------------------------------------------------------------------------
__global__ __launch_bounds__(1024) void k_build_f(
    const float* __restrict__ inp, const float* __restrict__ aspp,
    const float* __restrict__ f3g, const float* __restrict__ w_aspp,
    const float* __restrict__ w_f3, const float* __restrict__ w_f9,
    const float* __restrict__ cam,
    u16* __restrict__ fhi_g, u16* __restrict__ camA)
{
  const int y2 = blockIdx.x, n = blockIdx.y;
  const int tid = threadIdx.x;

  __shared__ __align__(16) u16 wh[128 * FT_STR];
  __shared__ __align__(16) u16 wl[128 * FT_STR];
  __shared__ __align__(16) u16 featA[128 * FT_STR];   // first used as xin
  __shared__ __align__(16) u16 c32[128 * C32_STR];    // [which*64+ch][px96]

  u16* xin = featA;   // xin[j(px96)][ch128], stride XI_STR; dead before feat

  // ---- P0: inline w_f9 split (k range padded to 160 with zeros)
  for (int e = tid; e < 128 * 160; e += 1024) {
    const int o = e / 160, c = e - o * 160;
    const float v = (c < 132) ? w_f9[o * 132 + c] : 0.f;
    const u16 h = f2bf(v);
    wh[o * FT_STR + c] = h;
    wl[o * FT_STR + c] = f2bf(v - bf2f(h));
  }
  // ---- camA side job
  {
    u16* dst = camA + ((size_t)n * 32 + y2) * HW64;
    if (y2 < KCAM) {
      const float* src = cam + ((size_t)n * KCAM + y2) * HW64;
      for (int i = tid; i < HW64; i += 1024) dst[i] = f2bf(src[i]);
    } else {
      const u16 v = (y2 == KCAM) ? f2bf(1.f) : (u16)0;
      for (int i = tid; i < HW64; i += 1024) dst[i] = v;
    }
  }

  // ---- bilinear params
  const float s512 = 511.f / 63.f, s32 = 31.f / 63.f;
  const int yA0i = y2 * 2, yA1i = y2 * 2 + 1;
  const float sA0 = yA0i * s512, sA1 = yA1i * s512;
  const int y0A0 = (int)sA0, y0A1 = (int)sA1;
  const float wyA0 = sA0 - y0A0, wyA1 = sA1 - y0A1;
  const int y1A0 = min(y0A0 + 1, 511), y1A1 = min(y0A1 + 1, 511);
  const float sB0 = yA0i * s32, sB1 = yA1i * s32;
  const int y0B0 = (int)sB0, y0B1 = (int)sB1;
  const float wyB0 = sB0 - y0B0, wyB1 = sB1 - y0B1;
  const int y1B0 = min(y0B0 + 1, 31), y1B1 = min(y0B1 + 1, 31);

  const int r0 = y0B0;
  const int sl0B0 = 0;
  const int sl1B0 = y1B0 - r0;
  const int sl0B1 = y0B1 - r0;
  const int sl1B1 = y1B1 - r0;

  const int lane = tid & 63, wave = tid >> 6;   // 16 waves
  const int l15 = lane & 15, l4 = lane >> 4;

  const int cm = wave & 3, chalf = (wave >> 2) & 1;

  // ---- P1/P2 (aspp) then P3/P4 (f3)
#pragma unroll
  for (int which = 0; which < 2; ++which) {
    const float* src = (which == 0 ? aspp : f3g) + (size_t)n * 128 * HW32;
    const float* wsrc = (which == 0 ? w_aspp : w_f3);

    for (int e = tid; e < 128 * 96; e += 1024) {
      const int ch = e / 96, j = e - ch * 96;
      const int rr = min(r0 + (j >> 5), 31);
      xin[j * XI_STR + ch] = f2bf(src[(size_t)ch * HW32 + rr * 32 + (j & 31)]);
    }
    __syncthreads();

    if (wave < 8) {
      f32x4 cacc[3];
#pragma unroll
      for (int pt = 0; pt < 3; ++pt) cacc[pt] = {0.f, 0.f, 0.f, 0.f};
#pragma unroll
      for (int s = 0; s < 4; ++s) {
        union { u16 h[8]; bf16x8 v; } Ahi, Alo;
        const float* wrow = wsrc + (cm * 16 + l15) * 128 + s * 32 + l4 * 8;
#pragma unroll
        for (int e = 0; e < 8; ++e) {
          const float v = wrow[e];
          const u16 h = f2bf(v);
          Ahi.h[e] = h;
          Alo.h[e] = f2bf(v - bf2f(h));
        }
#pragma unroll
        for (int pt = 0; pt < 3; ++pt) {
          const int px = (chalf * 3 + pt) * 16 + l15;
          const bf16x8 B = *(const bf16x8*)&xin[px * XI_STR + s * 32 + l4 * 8];
          cacc[pt] = __builtin_amdgcn_mfma_f32_16x16x32_bf16(Ahi.v, B, cacc[pt], 0, 0, 0);
          cacc[pt] = __builtin_amdgcn_mfma_f32_16x16x32_bf16(Alo.v, B, cacc[pt], 0, 0, 0);
        }
      }
#pragma unroll
      for (int pt = 0; pt < 3; ++pt) {
        const int px = (chalf * 3 + pt) * 16 + l15;
#pragma unroll
        for (int i = 0; i < 4; ++i)
          c32[(which * 64 + cm * 16 + l4 * 4 + i) * C32_STR + px] =
              f2bf(cacc[pt][i]);
      }
    }
    __syncthreads();
  }

  // ---- P5: feat sampling (c<4 global inp; c>=4 from c32 LDS)
  for (int idx = tid; idx < 132 * 128; idx += 1024) {
    const int c = idx >> 7;
    const int pos = idx & 127;
    const int ly = pos >> 6, x = pos & 63;
    float v;
    if (c < 4) {
      const int y0A = ly ? y0A1 : y0A0, y1A = ly ? y1A1 : y1A0;
      const float wyA = ly ? wyA1 : wyA0;
      const float sx = x * s512;
      const int x0 = (int)sx;
      const float wx = sx - (float)x0;
      const int x1 = min(x0 + 1, 511);
      const float* im = inp + (size_t)(n * 4 + c) * 512 * 512;
      const float v00 = im[y0A * 512 + x0], v01 = im[y0A * 512 + x1];
      const float v10 = im[y1A * 512 + x0], v11 = im[y1A * 512 + x1];
      v = (v00 * (1.f - wx) + v01 * wx) * (1.f - wyA) +
          (v10 * (1.f - wx) + v11 * wx) * wyA;
    } else {
      const int wh_ = (c < 68) ? 0 : 1;
      const int cc = (c < 68) ? (c - 4) : (c - 68);
      const int s0 = ly ? sl0B1 : sl0B0;
      const int s1 = ly ? sl1B1 : sl1B0;
      const float wyB = ly ? wyB1 : wyB0;
      const float sx = x * s32;
      const int x0 = (int)sx;
      const float wx = sx - (float)x0;
      const int x1 = min(x0 + 1, 31);
      const u16* row = &c32[(wh_ * 64 + cc) * C32_STR];
      const float v00 = bf2f(row[s0 * 32 + x0]), v01 = bf2f(row[s0 * 32 + x1]);
      const float v10 = bf2f(row[s1 * 32 + x0]), v11 = bf2f(row[s1 * 32 + x1]);
      v = (v00 * (1.f - wx) + v01 * wx) * (1.f - wyB) +
          (v10 * (1.f - wx) + v11 * wx) * wyB;
    }
    featA[pos * FT_STR + c] = f2bf(v);
  }
  for (int idx = tid; idx < 28 * 128; idx += 1024) {
    const int c = 132 + (idx >> 7), pos = idx & 127;
    featA[pos * FT_STR + c] = 0;
  }
  __syncthreads();

  // ---- P6: main MFMA (waves 0..7, each owns 16 positions), norm, store
  if (wave < 8) {
    float acc[8][4];
#pragma unroll
    for (int m = 0; m < 8; ++m)
#pragma unroll
      for (int i = 0; i < 4; ++i) acc[m][i] = 0.f;

#pragma unroll
    for (int s = 0; s < 5; ++s) {
      const bf16x8 B =
          *(const bf16x8*)&featA[(wave * 16 + l15) * FT_STR + s * 32 + l4 * 8];
#pragma unroll
      for (int m = 0; m < 8; ++m) {
        const int wo = (m * 16 + l15) * FT_STR + s * 32 + l4 * 8;
        const bf16x8 Ahi = *(const bf16x8*)&wh[wo];
        const bf16x8 Alo = *(const bf16x8*)&wl[wo];
        f32x4 a = {acc[m][0], acc[m][1], acc[m][2], acc[m][3]};
        a = __builtin_amdgcn_mfma_f32_16x16x32_bf16(Ahi, B, a, 0, 0, 0);
        a = __builtin_amdgcn_mfma_f32_16x16x32_bf16(Alo, B, a, 0, 0, 0);
        acc[m][0] = a[0]; acc[m][1] = a[1]; acc[m][2] = a[2]; acc[m][3] = a[3];
      }
    }

    float ss = 0.f;
#pragma unroll
    for (int m = 0; m < 8; ++m)
#pragma unroll
      for (int i = 0; i < 4; ++i) ss = fmaf(acc[m][i], acc[m][i], ss);
    ss += __shfl_xor(ss, 16);
    ss += __shfl_xor(ss, 32);
    const float inv = 1.f / (sqrtf(ss) + 1e-5f);
    const int pos = wave * 16 + l15;
    u16* fp = fhi_g + ((size_t)n * HW64 + (size_t)(y2 * 2 + (pos >> 6)) * 64 +
                       (pos & 63)) * 128 + l4 * 4;
#pragma unroll
    for (int m = 0; m < 8; ++m) {
      const float v0 = acc[m][0] * inv, v1 = acc[m][1] * inv;
      const float v2 = acc[m][2] * inv, v3 = acc[m][3] * inv;
      union { u32 d[2]; short4v h; } P;
      asm("v_cvt_pk_bf16_f32 %0, %1, %2" : "=v"(P.d[0]) : "v"(v0), "v"(v1));
      asm("v_cvt_pk_bf16_f32 %0, %1, %2" : "=v"(P.d[1]) : "v"(v2), "v"(v3));
      *(short4v*)(fp + m * 16) = P.h;
    }
  }
}

// ---------------------------------------------------------------------------
// Kernel C: fused affinity+cam (R22/R24 proven: 32x32x16 MFMA, zero-shuffle
// stage-2, PB=64, PSPLIT=4, async global_load_lds staging with pre-swizzled
// source, hoisted cam A-frags). grid 512 = 4ps x 16qt x 8n.
// ---------------------------------------------------------------------------
__global__ __launch_bounds__(256) void k_fused(
    const u16* __restrict__ fhi_g, const u16* __restrict__ camA,
    float* __restrict__ part)
{
  __shared__ __align__(16) u16 fh[2][PB * 128];   // 32 KB

  const int gx = blockIdx.x;
  const int n = gx & 7;
  const int rest = gx >> 3;
  const int qt = rest & 15;
  const int ps = rest >> 4;
  const int tid = threadIdx.x;
  const int lane = tid & 63;
  const int wq = tid >> 6;
  const int l31 = lane & 31;
  const int lh = lane >> 5;
  const int qb = qt * 256;

  const u16* fbase = fhi_g + (size_t)n * HW64 * 128;

  bf16x8 Bq[2][8];
#pragma unroll
  for (int qh = 0; qh < 2; ++qh) {
    const size_t rowo = (size_t)(qb + wq * 64 + qh * 32 + l31) * 128;
#pragma unroll
    for (int ks = 0; ks < 8; ++ks)
      Bq[qh][ks] = *(const bf16x8*)(fbase + rowo + ks * 16 + lh * 8);
  }

  f32x16 nacc0, nacc1;
#pragma unroll
  for (int i = 0; i < 16; ++i) { nacc0[i] = 0.f; nacc1[i] = 0.f; }

  const int p_base = ps * (HW64 / PSPLIT);
  const int xorr = (l31 & 7) << 4;

  const int srow0 = (lane >> 4);
  const int scbl = (lane & 15) * 16;

#pragma unroll
  for (int s = 0; s < 4; ++s) {
    const int rr = (wq * 4 + s) * 4 + srow0;
    const u16* gsrc = fbase + (size_t)(p_base + rr) * 128 +
                      ((scbl ^ ((rr & 7) << 4)) >> 1);
    GLOAD_LDS16(gsrc, &fh[0][(wq * 4 + s) * 512]);
  }

  int cur = 0;
  for (int t = 0; t < (HW64 / PSPLIT) / PB; ++t) {   // 16 tiles
    const int p0 = p_base + t * PB;
    __syncthreads();

    if (t < 15) {
#pragma unroll
      for (int s = 0; s < 4; ++s) {
        const int rr = (wq * 4 + s) * 4 + srow0;
        const u16* gsrc = fbase + (size_t)(p0 + PB + rr) * 128 +
                          ((scbl ^ ((rr & 7) << 4)) >> 1);
        GLOAD_LDS16(gsrc, &fh[cur ^ 1][(wq * 4 + s) * 512]);
      }
    }

    bf16x8 Ac[4];
#pragma unroll
    for (int kst = 0; kst < 4; ++kst) {
      union { short4v h[2]; bf16x8 v; } A;
      const u16* cp = camA + ((size_t)n * 32 + l31) * HW64 + p0 + kst * 16 + lh * 4;
      A.h[0] = *(const short4v*)cp;
      A.h[1] = *(const short4v*)(cp + 8);
      Ac[kst] = A.v;
    }

    f32x16 accS[2][2];
#pragma unroll
    for (int ks = 0; ks < 8; ++ks) {
      const int cb = (ks * 32 + (lh << 4)) ^ xorr;
      bf16x8 Ah[2];
#pragma unroll
      for (int mt = 0; mt < 2; ++mt)
        Ah[mt] = *(const bf16x8*)&fh[cur][(mt * 32 + l31) * 128 + (cb >> 1)];
      if (ks == 0) {
        f32x16 z;
#pragma unroll
        for (int i = 0; i < 16; ++i) z[i] = 0.f;
#pragma unroll
        for (int mt = 0; mt < 2; ++mt) {
          accS[mt][0] = __builtin_amdgcn_mfma_f32_32x32x16_bf16(Ah[mt], Bq[0][0], z, 0, 0, 0);
          accS[mt][1] = __builtin_amdgcn_mfma_f32_32x32x16_bf16(Ah[mt], Bq[1][0], z, 0, 0, 0);
        }
      } else {
#pragma unroll
        for (int mt = 0; mt < 2; ++mt) {
          accS[mt][0] = __builtin_amdgcn_mfma_f32_32x32x16_bf16(Ah[mt], Bq[0][ks], accS[mt][0], 0, 0, 0);
          accS[mt][1] = __builtin_amdgcn_mfma_f32_32x32x16_bf16(Ah[mt], Bq[1][ks], accS[mt][1], 0, 0, 0);
        }
      }
    }

#pragma unroll
    for (int kst = 0; kst < 4; ++kst) {
      const int mt = kst >> 1, h8 = (kst & 1) * 8;
#pragma unroll
      for (int qh = 0; qh < 2; ++qh) {
        union { u32 d[4]; bf16x8 v; } W;
#pragma unroll
        for (int i = 0; i < 4; ++i) {
          const float a0 = fmaxf(accS[mt][qh][h8 + 2 * i], 0.f);
          const float a1 = fmaxf(accS[mt][qh][h8 + 2 * i + 1], 0.f);
          asm("v_cvt_pk_bf16_f32 %0, %1, %2" : "=v"(W.d[i]) : "v"(a0), "v"(a1));
        }
        if (qh == 0)
          nacc0 = __builtin_amdgcn_mfma_f32_32x32x16_bf16(Ac[kst], W.v, nacc0, 0, 0, 0);
        else
          nacc1 = __builtin_amdgcn_mfma_f32_32x32x16_bf16(Ac[kst], W.v, nacc1, 0, 0, 0);
      }
    }

    cur ^= 1;
  }

#pragma unroll
  for (int qh = 0; qh < 2; ++qh) {
    const int qg = qb + wq * 64 + qh * 32 + l31;
#pragma unroll
    for (int r = 0; r < 16; ++r) {
      const int row = (r & 3) + 8 * (r >> 2) + 4 * lh;
      if (row < 22)
        part[(((size_t)n * PSPLIT + ps) * 22 + row) * HW64 + qg] =
            (qh == 0) ? nacc0[r] : nacc1[r];
    }
  }
}

// ---------------------------------------------------------------------------
// Kernel D: combine PSPLIT partials, divide. float4 per thread.
// ---------------------------------------------------------------------------
__global__ __launch_bounds__(256) void k_final(
    const float* __restrict__ part, float* __restrict__ out, int total4)
{
  const int idx = blockIdx.x * 256 + threadIdx.x;
  if (idx >= total4) return;
  const int n = idx / (KCAM * 1024);
  const int r = idx - n * (KCAM * 1024);
  const int k = r >> 10;
  const int q4 = (r & 1023) * 4;
  const float* base = part + (size_t)n * PSPLIT * 22 * HW64;
  float4 num = {0.f, 0.f, 0.f, 0.f}, den = {0.f, 0.f, 0.f, 0.f};
#pragma unroll
  for (int p = 0; p < PSPLIT; ++p) {
    const float4 nv = *reinterpret_cast<const float4*>(
        &base[((size_t)p * 22 + k) * HW64 + q4]);
    const float4 dv = *reinterpret_cast<const float4*>(
        &base[((size_t)p * 22 + 21) * HW64 + q4]);
    num.x += nv.x; num.y += nv.y; num.z += nv.z; num.w += nv.w;
    den.x += dv.x; den.y += dv.y; den.z += dv.z; den.w += dv.w;
  }
  float4 o;
  o.x = num.x / (den.x + 1e-5f);
  o.y = num.y / (den.y + 1e-5f);
  o.z = num.z / (den.z + 1e-5f);
  o.w = num.w / (den.w + 1e-5f);
  *reinterpret_cast<float4*>(&out[((size_t)n * KCAM + k) * HW64 + q4]) = o;
}

// ---------------------------------------------------------------------------
extern "C" void kernel_launch(void* const* d_in, const int* in_sizes, int n_in,
                              void* d_out, int out_size, void* d_ws, size_t ws_size,
                              hipStream_t stream) {
  const float* aspp   = (const float*)d_in[0];
  const float* f3     = (const float*)d_in[1];
  const float* inp    = (const float*)d_in[2];
  const float* cam    = (const float*)d_in[3];
  const float* w_aspp = (const float*)d_in[4];
  const float* w_f3   = (const float*)d_in[5];
  const float* w_f9   = (const float*)d_in[6];
  float* out = (float*)d_out;

  // Workspace (~21.5 MB):
  //   [0, 8MB)    fhi  (u16, 8*4096*128)   k_build_f
  //   [8, 10MB)   camA (u16, 8*32*4096)    k_build_f side job
  //   then part (f32, 8*4*22*4096 = 11.5MB)  k_fused
  u16*   fhi  = (u16*)d_ws;
  u16*   camA = fhi + 4194304;
  float* part = (float*)(camA + 1048576);

  k_build_f<<<dim3(32, 8), 1024, 0, stream>>>(inp, aspp, f3, w_aspp, w_f3,
                                              w_f9, cam, fhi, camA);
  k_fused<<<512, 256, 0, stream>>>(fhi, camA, part);
  k_final<<<672, 256, 0, stream>>>(part, out, 8 * KCAM * 1024);
}